// Round 15
// baseline (281.287 us; speedup 1.0000x reference)
//
#include <hip/hip_runtime.h>

// ---------------------------------------------------------------------------
// 2-layer LSTM (BN=8192 seqs, T=64, F=16, H=128) + graph mixing stage.
// LSTM stage = round 13 exact (best verified: 260.8us total, issue-bound
// model closes at 97%): 16x16x32 MFMA, 32 rows/block, 16 waves, (1024,4),
// T5 setprio, XOR-swizzled LDS h-state, coalesced h1 bounce, 5exp+2rcp cell.
// Round 15 delta: g1..g4 fused into ONE kernel (g_all), one block per batch b
// (grid 32 x 1024). HA and mid/W3r live in LDS (2x64KB, XOR swizzle);
// W1hA kept in VGPRs between phase2 and phase4 (same wave->tile mapping).
// Removes 3 launches + 8MB of intermediate HBM round-trips.
// MFMA frag conventions (verified rounds 1-13):
//   A-frag: lane l holds A[16*rt + (l&15)][32*kt + 8*(l>>4) + i], i=0..7
//   B-frag: lane l holds B[32*kt + 8*(l>>4) + i][16*ct + (l&15)]
//   D:      lane l, reg r holds D[16*rt + 4*(l>>4) + r][16*ct + (l&15)]
// ---------------------------------------------------------------------------

typedef __attribute__((ext_vector_type(4))) float f32x4;
typedef __attribute__((ext_vector_type(2))) float f32x2;
typedef __attribute__((ext_vector_type(8))) __bf16 bf16x8;
typedef __attribute__((ext_vector_type(8))) unsigned short u16x8;
typedef __attribute__((ext_vector_type(4))) unsigned short u16x4;

#define DEV static __device__ __forceinline__

DEV unsigned short f2bf(float f) {
  unsigned u = __builtin_bit_cast(unsigned, f);
  u = u + 0x7fffu + ((u >> 16) & 1u);
  return (unsigned short)(u >> 16);
}
DEV float bf2f(unsigned short s) {
  unsigned u = ((unsigned)s) << 16;
  return __builtin_bit_cast(float, u);
}

DEV float fexp2(float x) { return __builtin_amdgcn_exp2f(x); }   // raw v_exp_f32
DEV f32x2 exp2v2(f32x2 x) { f32x2 r; r[0] = fexp2(x[0]); r[1] = fexp2(x[1]); return r; }
DEV f32x2 rcpv2(f32x2 x) {
  f32x2 r; r[0] = __builtin_amdgcn_rcpf(x[0]); r[1] = __builtin_amdgcn_rcpf(x[1]); return r;
}

// Two independent LSTM cells in packed f32x2 lanes; 5 exp2 + 2 rcp per cell.
// Gates PRE-SCALED: i,f,o by log2(e); g by 2*log2(e).  cs = 2*log2(e)*c.
DEV unsigned cell_pair(f32x2 gi, f32x2 gf, f32x2 gg, f32x2 go, f32x2& cs) {
  const float K2 = 2.88539008f;
  f32x2 one = {1.f, 1.f};
  f32x2 t1 = exp2v2(gg);                               // e^{2g}
  f32x2 t2 = exp2v2((f32x2){-gi[0], -gi[1]});          // e^{-i}
  f32x2 ef = exp2v2((f32x2){-gf[0], -gf[1]});          // e^{-f}
  f32x2 d1 = t1 + one;
  f32x2 den1 = d1 * t2 + d1;                           // (t1+1)(1+e^{-i})
  f32x2 e1 = one + ef;
  f32x2 num = cs * den1 + (f32x2){K2, K2} * (t1 - one) * e1;
  cs = num * rcpv2(e1 * den1);
  f32x2 t3 = exp2v2(cs);                               // e^{2c}
  f32x2 t4 = exp2v2((f32x2){-go[0], -go[1]});          // e^{-o}
  f32x2 d3 = t3 + one;
  f32x2 den3 = d3 * t4 + d3;
  f32x2 h = (t3 - one) * rcpv2(den3);                  // sig(o)*tanh(c)
  unsigned r;
  asm("v_cvt_pk_bf16_f32 %0, %1, %2" : "=v"(r) : "v"(h[0]), "v"(h[1]));
  return r;
}

// ---------------- workspace layout (bytes) ----------------
#define O_W0PK   0            // 163840
#define O_W1PK   163840       // 262144
#define O_APK    425984       // 131072
#define O_W1APK  557056       // 32768
#define O_W2APK  589824       // 32768
#define O_W3APK  622592       // 32768
#define O_BIAS0  655360       // 2048
#define O_BIAS1  657408       // 2048 (pre-scaled)
#define O_HTT    659456       // 2097152  hT^T [32][128][256] bf16
#define O_XPK    11145216     // 33554432 x B-frags (padded K=32, pad col16=1.0)
#define O_H1     44699648     // up to 128 MiB h1 [row][t][128] bf16

#define PREPX_TOT 2097152
#define PREP_TOT  328704
#define PREPALL_TOT (PREPX_TOT + PREP_TOT)

// unit for packed gate-row tile rt, lane-quad lq, within-pair s = rt&1
DEV int gr_unit(int rt, int lq2, int s) { return 8 * (rt >> 1) + 2 * lq2 + s; }

// ---------------- merged prepass: x frags + weight packs -------------------
__global__ void prep_all(const float* __restrict__ x, const float* __restrict__ A,
    const float* __restrict__ Wih0, const float* __restrict__ Whh0,
    const float* __restrict__ bih0, const float* __restrict__ bhh0,
    const float* __restrict__ Wih1, const float* __restrict__ Whh1,
    const float* __restrict__ bih1, const float* __restrict__ bhh1,
    const float* __restrict__ W1, const float* __restrict__ W2,
    const float* __restrict__ W3, char* __restrict__ ws)
{
  const float K1 = 1.44269504f, K2 = 2.88539008f;
  int gidx = blockIdx.x * blockDim.x + threadIdx.x;
  if (gidx < PREPX_TOT) {                  // x -> padded B-frag bf16
    int tid = gidx;
    int dat = (tid < 1048576) ? 1 : 0;
    int id = tid & 1048575;
    int half = id & 1, t = (id >> 1) & 63, row = id >> 7;
    u16x8 v = (u16x8)0;
    if (dat) {
      const float* p = x + ((long)row * 64 + t) * 16 + 8 * half;
      float4 a = *(const float4*)p;
      float4 b = *(const float4*)(p + 4);
      v[0] = f2bf(a.x); v[1] = f2bf(a.y); v[2] = f2bf(a.z); v[3] = f2bf(a.w);
      v[4] = f2bf(b.x); v[5] = f2bf(b.y); v[6] = f2bf(b.z); v[7] = f2bf(b.w);
    } else if (half == 0) {
      v[0] = 0x3F80;                            // k=16 -> 1.0f (bias column)
    }
    int lane = (dat ? 0 : 32) + half * 16 + (row & 15);
    int rt = row >> 4;
    ((u16x8*)(ws + O_XPK))[(rt * 64 + t) * 64 + lane] = v;
    return;
  }
  int idx = gidx - PREPX_TOT;
  if (idx >= PREP_TOT) return;
  if (idx < 81920) {                       // W0pk A-frags
    int o = idx, i = o & 7, l = (o >> 3) & 63, f = o >> 9;
    int kt = f % 5, rt = f / 5;
    int lr = l & 15, lq = l >> 4;
    int p = lr & 3, lql = (lr >> 2) & 3;
    int gc = p * 128 + gr_unit(rt, lql, rt & 1);
    float sc = (p == 2) ? K2 : K1;
    float v;
    if (kt < 4) v = Whh0[gc * 128 + 32 * kt + 8 * lq + i];
    else {
      int kk = 8 * lq + i;
      v = (kk < 16) ? Wih0[gc * 16 + kk]
                    : (kk == 16 ? (bih0[gc] + bhh0[gc]) : 0.f);  // bias row
    }
    ((unsigned short*)(ws + O_W0PK))[idx] = f2bf(v * sc);
  } else if (idx < 212992) {               // W1pk: kt<4 = h1-input, kt>=4 = recurrent
    int o = idx - 81920, i = o & 7, l = (o >> 3) & 63, f = o >> 9;
    int kt = f & 7, rt = f >> 3;
    int lr = l & 15, lq = l >> 4;
    int p = lr & 3, lql = (lr >> 2) & 3;
    int gc = p * 128 + gr_unit(rt, lql, rt & 1);
    float sc = (p == 2) ? K2 : K1;
    float v = (kt < 4) ? Wih1[gc * 128 + 32 * kt + 8 * lq + i]
                       : Whh1[gc * 128 + 32 * (kt - 4) + 8 * lq + i];
    ((unsigned short*)(ws + O_W1PK))[o] = f2bf(v * sc);
  } else if (idx < 278528) {               // Apk = sigmoid(A) B-frags
    int o = idx - 212992, i = o & 7, l = (o >> 3) & 63, f = o >> 9;
    int kt = f & 7, ct = f >> 3;
    int n = 32 * kt + 8 * (l >> 4) + i;
    int lc = 16 * ct + (l & 15);
    float e = fexp2(-K1 * A[n * 256 + lc]);
    ((unsigned short*)(ws + O_APK))[o] = f2bf(__builtin_amdgcn_rcpf(1.f + e));
  } else if (idx < 327680) {               // W1/W2/W3 A-frags (graph stage)
    int o = idx - 278528;
    int m = o >> 14;
    int oo = o & 16383;
    int i = oo & 7, l = (oo >> 3) & 63, f = oo >> 9;
    int kt = f & 3, rt = f >> 2;
    int g = 16 * rt + (l & 15);
    int k = 32 * kt + 8 * (l >> 4) + i;
    const float* W = (m == 0) ? W1 : (m == 1) ? W2 : W3;
    unsigned short* dst = (unsigned short*)(ws + ((m == 0) ? O_W1APK : (m == 1) ? O_W2APK : O_W3APK));
    dst[oo] = f2bf(W[g * 128 + k]);
  } else if (idx < 328192) {
    int c = idx - 327680;
    ((float*)(ws + O_BIAS0))[c] = bih0[c] + bhh0[c];
  } else {                                 // BIAS1: pre-scaled by gate
    int c = idx - 328192;
    float sc = ((c >> 7) == 2) ? K2 : K1;
    ((float*)(ws + O_BIAS1))[c] = (bih1[c] + bhh1[c]) * sc;
  }
}

// ---------------- LSTM layer 0: 32 rows/block, 16 waves (r13 exact) --------
__global__ __launch_bounds__(1024, 4) void lstm0_k(char* __restrict__ ws, int row_base)
{
  const unsigned short* W0pk = (const unsigned short*)(ws + O_W0PK);
  const unsigned short* xpk = (const unsigned short*)(ws + O_XPK);
  unsigned short* h1 = (unsigned short*)(ws + O_H1);

  int tid = threadIdx.x;
  int Wv = tid >> 6, l = tid & 63, lr = l & 15, lq = l >> 4;
  int lrow = blockIdx.x * 32;
  long grow0 = (long)row_base + lrow;

  __shared__ unsigned char hlds[2][8192];
  ((u16x8*)hlds[0])[tid] = (u16x8)0;

  bf16x8 Af[2][5];
#pragma unroll
  for (int s = 0; s < 2; s++)
#pragma unroll
    for (int kt = 0; kt < 5; kt++)
      Af[s][kt] = ((const bf16x8*)W0pk)[(((2 * Wv + s) * 5) + kt) * 64 + l];

  f32x2 c_st[2] = {{0.f, 0.f}, {0.f, 0.f}};

  int rd[2][4], whp[2];
#pragma unroll
  for (int ct = 0; ct < 2; ct++) {
#pragma unroll
    for (int kt = 0; kt < 4; kt++)
      rd[ct][kt] = (16 * ct + lr) * 256 + ((64 * kt + 16 * lq) ^ ((lr & 7) << 4));
    whp[ct] = (16 * ct + lr) * 256 + ((16 * Wv + 4 * lq) ^ ((lr & 7) << 4));
  }

  int pr = tid >> 6, sj = tid & 63;
  int sld0 = pr * 256 + ((4 * sj) ^ ((pr & 7) << 4));
  int sld1 = (pr + 16) * 256 + ((4 * sj) ^ ((pr & 7) << 4));
  unsigned short* st0 = h1 + (long)(lrow + pr) * 8192 + 2 * sj;
  unsigned short* st1 = h1 + (long)(lrow + pr + 16) * 8192 + 2 * sj;

  const bf16x8* xp0 = (const bf16x8*)xpk + ((grow0 >> 4) + 0) * 4096 + l;
  const bf16x8* xp1 = (const bf16x8*)xpk + ((grow0 >> 4) + 1) * 4096 + l;
  bf16x8 xb[2] = {xp0[0], xp1[0]};
  __syncthreads();

  for (int t = 0; t < 64; t++) {
    const unsigned char* rbuf = hlds[t & 1];
    unsigned char* wbuf = hlds[(t & 1) ^ 1];
    int tn = (t < 63) ? t + 1 : 63;
    bf16x8 xbn0 = xp0[tn * 64];
    bf16x8 xbn1 = xp1[tn * 64];

    f32x4 acc[2][2];
#pragma unroll
    for (int ct = 0; ct < 2; ct++)
#pragma unroll
      for (int s = 0; s < 2; s++) acc[ct][s] = (f32x4){0.f, 0.f, 0.f, 0.f};
    __builtin_amdgcn_s_setprio(1);
#pragma unroll
    for (int kt = 0; kt < 4; kt++) {
      bf16x8 hb0 = *(const bf16x8*)(rbuf + rd[0][kt]);
      bf16x8 hb1 = *(const bf16x8*)(rbuf + rd[1][kt]);
      acc[0][0] = __builtin_amdgcn_mfma_f32_16x16x32_bf16(Af[0][kt], hb0, acc[0][0], 0, 0, 0);
      acc[0][1] = __builtin_amdgcn_mfma_f32_16x16x32_bf16(Af[1][kt], hb0, acc[0][1], 0, 0, 0);
      acc[1][0] = __builtin_amdgcn_mfma_f32_16x16x32_bf16(Af[0][kt], hb1, acc[1][0], 0, 0, 0);
      acc[1][1] = __builtin_amdgcn_mfma_f32_16x16x32_bf16(Af[1][kt], hb1, acc[1][1], 0, 0, 0);
    }
    acc[0][0] = __builtin_amdgcn_mfma_f32_16x16x32_bf16(Af[0][4], xb[0], acc[0][0], 0, 0, 0);
    acc[0][1] = __builtin_amdgcn_mfma_f32_16x16x32_bf16(Af[1][4], xb[0], acc[0][1], 0, 0, 0);
    acc[1][0] = __builtin_amdgcn_mfma_f32_16x16x32_bf16(Af[0][4], xb[1], acc[1][0], 0, 0, 0);
    acc[1][1] = __builtin_amdgcn_mfma_f32_16x16x32_bf16(Af[1][4], xb[1], acc[1][1], 0, 0, 0);
    __builtin_amdgcn_s_setprio(0);
#pragma unroll
    for (int ct = 0; ct < 2; ct++) {
      f32x2 gi = {acc[ct][0][0], acc[ct][1][0]};
      f32x2 gf = {acc[ct][0][1], acc[ct][1][1]};
      f32x2 gg = {acc[ct][0][2], acc[ct][1][2]};
      f32x2 go = {acc[ct][0][3], acc[ct][1][3]};
      *(unsigned*)(wbuf + whp[ct]) = cell_pair(gi, gf, gg, go, c_st[ct]);
    }
    xb[0] = xbn0; xb[1] = xbn1;
    __syncthreads();
    *(unsigned*)(st0 + t * 128) = *(const unsigned*)(hlds[(t & 1) ^ 1] + sld0);
    *(unsigned*)(st1 + t * 128) = *(const unsigned*)(hlds[(t & 1) ^ 1] + sld1);
  }
}

// ---------------- LSTM layer 1: 32 rows/block, 16 waves (r13 exact) --------
__global__ __launch_bounds__(1024, 4) void lstm1_k(char* __restrict__ ws, int row_base)
{
  const unsigned short* W1pk = (const unsigned short*)(ws + O_W1PK);
  const float* bias1 = (const float*)(ws + O_BIAS1);
  const unsigned short* h1 = (const unsigned short*)(ws + O_H1);
  unsigned short* hTt = (unsigned short*)(ws + O_HTT);

  int tid = threadIdx.x;
  int Wv = tid >> 6, l = tid & 63, lr = l & 15, lq = l >> 4;
  int lrow = blockIdx.x * 32;
  long grow0 = (long)row_base + lrow;

  __shared__ unsigned char hlds[2][8192];
  __shared__ unsigned char h1s[2][8192];
  ((u16x8*)hlds[0])[tid] = (u16x8)0;

  int prow = tid >> 6, pc = tid & 63;
  const unsigned short* s0 = h1 + (long)(lrow + prow) * 8192 + 2 * pc;
  const unsigned short* s1 = h1 + (long)(lrow + prow + 16) * 8192 + 2 * pc;
  int d0 = prow * 256 + ((4 * pc) ^ ((prow & 7) << 4));
  int d1 = (prow + 16) * 256 + ((4 * pc) ^ ((prow & 7) << 4));
  *(unsigned*)(h1s[0] + d0) = *(const unsigned*)s0;
  *(unsigned*)(h1s[0] + d1) = *(const unsigned*)s1;

  bf16x8 Af[2][8];
#pragma unroll
  for (int s = 0; s < 2; s++)
#pragma unroll
    for (int kt = 0; kt < 8; kt++)
      Af[s][kt] = ((const bf16x8*)W1pk)[(((2 * Wv + s) * 8) + kt) * 64 + l];

  f32x4 bias_c[2];
#pragma unroll
  for (int s = 0; s < 2; s++)
#pragma unroll
    for (int r = 0; r < 4; r++)
      bias_c[s][r] = bias1[r * 128 + 8 * Wv + 2 * lq + s];

  f32x2 c_st[2] = {{0.f, 0.f}, {0.f, 0.f}};

  int rd[2][4], whp[2];
#pragma unroll
  for (int ct = 0; ct < 2; ct++) {
#pragma unroll
    for (int kt = 0; kt < 4; kt++)
      rd[ct][kt] = (16 * ct + lr) * 256 + ((64 * kt + 16 * lq) ^ ((lr & 7) << 4));
    whp[ct] = (16 * ct + lr) * 256 + ((16 * Wv + 4 * lq) ^ ((lr & 7) << 4));
  }
  __syncthreads();

  for (int t = 0; t < 64; t++) {
    const unsigned char* rbuf = hlds[t & 1];
    unsigned char* wbuf = hlds[(t & 1) ^ 1];
    const unsigned char* h1r = h1s[t & 1];
    unsigned char* h1w = h1s[(t & 1) ^ 1];
    int tn = (t < 63) ? t + 1 : 63;
    unsigned pf0 = *(const unsigned*)(s0 + tn * 128);
    unsigned pf1 = *(const unsigned*)(s1 + tn * 128);

    f32x4 acc[2][2];
#pragma unroll
    for (int ct = 0; ct < 2; ct++) {
      acc[ct][0] = bias_c[0]; acc[ct][1] = bias_c[1];
    }
    __builtin_amdgcn_s_setprio(1);
#pragma unroll
    for (int kt = 0; kt < 4; kt++) {
      bf16x8 xb0 = *(const bf16x8*)(h1r + rd[0][kt]);
      bf16x8 xb1 = *(const bf16x8*)(h1r + rd[1][kt]);
      acc[0][0] = __builtin_amdgcn_mfma_f32_16x16x32_bf16(Af[0][kt], xb0, acc[0][0], 0, 0, 0);
      acc[0][1] = __builtin_amdgcn_mfma_f32_16x16x32_bf16(Af[1][kt], xb0, acc[0][1], 0, 0, 0);
      acc[1][0] = __builtin_amdgcn_mfma_f32_16x16x32_bf16(Af[0][kt], xb1, acc[1][0], 0, 0, 0);
      acc[1][1] = __builtin_amdgcn_mfma_f32_16x16x32_bf16(Af[1][kt], xb1, acc[1][1], 0, 0, 0);
    }
#pragma unroll
    for (int kt = 0; kt < 4; kt++) {
      bf16x8 hb0 = *(const bf16x8*)(rbuf + rd[0][kt]);
      bf16x8 hb1 = *(const bf16x8*)(rbuf + rd[1][kt]);
      acc[0][0] = __builtin_amdgcn_mfma_f32_16x16x32_bf16(Af[0][4 + kt], hb0, acc[0][0], 0, 0, 0);
      acc[0][1] = __builtin_amdgcn_mfma_f32_16x16x32_bf16(Af[1][4 + kt], hb0, acc[0][1], 0, 0, 0);
      acc[1][0] = __builtin_amdgcn_mfma_f32_16x16x32_bf16(Af[0][4 + kt], hb1, acc[1][0], 0, 0, 0);
      acc[1][1] = __builtin_amdgcn_mfma_f32_16x16x32_bf16(Af[1][4 + kt], hb1, acc[1][1], 0, 0, 0);
    }
    __builtin_amdgcn_s_setprio(0);
#pragma unroll
    for (int ct = 0; ct < 2; ct++) {
      f32x2 gi = {acc[ct][0][0], acc[ct][1][0]};
      f32x2 gf = {acc[ct][0][1], acc[ct][1][1]};
      f32x2 gg = {acc[ct][0][2], acc[ct][1][2]};
      f32x2 go = {acc[ct][0][3], acc[ct][1][3]};
      *(unsigned*)(wbuf + whp[ct]) = cell_pair(gi, gf, gg, go, c_st[ct]);
    }
    *(unsigned*)(h1w + d0) = pf0;
    *(unsigned*)(h1w + d1) = pf1;
    __syncthreads();
  }

#pragma unroll
  for (int ct = 0; ct < 2; ct++) {
    unsigned hp = *(const unsigned*)(hlds[0] + whp[ct]);
    long grow = grow0 + 16 * ct + lr;
    long base = ((grow >> 8) * 128) * 256 + (grow & 255);
    int u0 = 8 * Wv + 2 * lq;
    hTt[base + (long)u0 * 256] = (unsigned short)(hp & 0xffff);
    hTt[base + (long)(u0 + 1) * 256] = (unsigned short)(hp >> 16);
  }
}

// ---------------- fused graph stage: one block per batch b -----------------
// P1: HA = hTt_b @ Apk          -> lA as [n][h] (swz8)
// P2: a1 = W1@HA (kept in regs as bf16), mid = relu(W2@HA) -> lB [n][g] (swz8)
// P3: W3r = W3@mid              -> lA reused as [f][n] (swz16, A-frag layout)
// P4: ATW = W3r@Apk; hout = 0.1*ATW + 0.9*a1; out = sigmoid(Wfc . hout)
// Wave w owns ct = w (16 output cols), rt = 0..7 in every phase, so P2's a1
// D-tiles are lane-aligned with P4's epilogue needs.
__global__ __launch_bounds__(1024, 4) void g_all(char* __restrict__ ws,
    const float* __restrict__ Wfc, float* __restrict__ out)
{
  const unsigned short* hTt = (const unsigned short*)(ws + O_HTT);
  const unsigned short* Apk = (const unsigned short*)(ws + O_APK);
  const unsigned short* W1apk = (const unsigned short*)(ws + O_W1APK);
  const unsigned short* W2apk = (const unsigned short*)(ws + O_W2APK);
  const unsigned short* W3apk = (const unsigned short*)(ws + O_W3APK);

  __shared__ unsigned char lA[65536];
  __shared__ unsigned char lB[65536];

  int tid = threadIdx.x;
  int ct = tid >> 6, l = tid & 63, lr = l & 15, lq = l >> 4;
  int b = blockIdx.x;
  int nrow = 16 * ct + lr;                      // this lane's output column/row n

  // ---- P1: HA[h=128][n=256] tiles -> lA [n][h] swz8 ----
  f32x4 acc[8];
#pragma unroll
  for (int rt = 0; rt < 8; rt++) acc[rt] = (f32x4){0.f, 0.f, 0.f, 0.f};
  for (int kt = 0; kt < 8; kt++) {
    bf16x8 bfv = ((const bf16x8*)Apk)[(ct * 8 + kt) * 64 + l];
#pragma unroll
    for (int rt = 0; rt < 8; rt++) {
      bf16x8 af = *(const bf16x8*)(hTt + (long)(b * 128 + 16 * rt + lr) * 256 + 32 * kt + 8 * lq);
      acc[rt] = __builtin_amdgcn_mfma_f32_16x16x32_bf16(af, bfv, acc[rt], 0, 0, 0);
    }
  }
#pragma unroll
  for (int rt = 0; rt < 8; rt++) {
    u16x4 pk;
#pragma unroll
    for (int r = 0; r < 4; r++) pk[r] = f2bf(acc[rt][r]);
    *(u16x4*)(lA + nrow * 256 + ((32 * rt + 8 * lq) ^ ((lr & 7) << 4))) = pk;
  }
  __syncthreads();

  // ---- P2: a1 = W1@HA (regs), mid = relu(W2@HA) -> lB ----
  int rdH[4];
#pragma unroll
  for (int kt = 0; kt < 4; kt++)
    rdH[kt] = nrow * 256 + ((64 * kt + 16 * lq) ^ ((lr & 7) << 4));

  f32x4 a2[8];
#pragma unroll
  for (int rt = 0; rt < 8; rt++) { acc[rt] = (f32x4){0.f,0.f,0.f,0.f}; a2[rt] = (f32x4){0.f,0.f,0.f,0.f}; }
  for (int kt = 0; kt < 4; kt++) {
    bf16x8 bfv = *(const bf16x8*)(lA + rdH[kt]);
#pragma unroll
    for (int rt = 0; rt < 8; rt++) {
      bf16x8 af1 = ((const bf16x8*)W1apk)[(rt * 4 + kt) * 64 + l];
      bf16x8 af2 = ((const bf16x8*)W2apk)[(rt * 4 + kt) * 64 + l];
      acc[rt] = __builtin_amdgcn_mfma_f32_16x16x32_bf16(af1, bfv, acc[rt], 0, 0, 0);
      a2[rt]  = __builtin_amdgcn_mfma_f32_16x16x32_bf16(af2, bfv, a2[rt], 0, 0, 0);
    }
  }
  u16x4 a1s[8];                               // W1hA kept lane-local as bf16
#pragma unroll
  for (int rt = 0; rt < 8; rt++) {
    u16x4 p1, p2;
#pragma unroll
    for (int r = 0; r < 4; r++) {
      p1[r] = f2bf(acc[rt][r]);
      p2[r] = f2bf(fmaxf(a2[rt][r], 0.f));
    }
    a1s[rt] = p1;
    *(u16x4*)(lB + nrow * 256 + ((32 * rt + 8 * lq) ^ ((lr & 7) << 4))) = p2;
  }
  __syncthreads();

  // ---- P3: W3r = W3@mid -> lA as [f][n] swz16 ----
#pragma unroll
  for (int rt = 0; rt < 8; rt++) acc[rt] = (f32x4){0.f, 0.f, 0.f, 0.f};
  for (int kt = 0; kt < 4; kt++) {
    bf16x8 bfv = *(const bf16x8*)(lB + rdH[kt]);
#pragma unroll
    for (int rt = 0; rt < 8; rt++) {
      bf16x8 af3 = ((const bf16x8*)W3apk)[(rt * 4 + kt) * 64 + l];
      acc[rt] = __builtin_amdgcn_mfma_f32_16x16x32_bf16(af3, bfv, acc[rt], 0, 0, 0);
    }
  }
  __syncthreads();                             // all P3 reads of lB... (lA being rewritten)
#pragma unroll
  for (int rt = 0; rt < 8; rt++) {
#pragma unroll
    for (int r = 0; r < 4; r++) {
      int f = 16 * rt + 4 * lq + r;
      *(unsigned short*)(lA + f * 512 + ((2 * nrow) ^ ((f & 15) << 4))) = f2bf(acc[rt][r]);
    }
  }
  __syncthreads();

  // ---- P4: ATW = W3r@Apk; hout = 0.1*ATW + 0.9*a1; reduce with Wfc ----
#pragma unroll
  for (int rt = 0; rt < 8; rt++) acc[rt] = (f32x4){0.f, 0.f, 0.f, 0.f};
  for (int kt = 0; kt < 8; kt++) {
    bf16x8 bfv = ((const bf16x8*)Apk)[(ct * 8 + kt) * 64 + l];
#pragma unroll
    for (int rt = 0; rt < 8; rt++) {
      bf16x8 af = *(const bf16x8*)(lA + (16 * rt + lr) * 512 + ((64 * kt + 16 * lq) ^ (lr << 4)));
      acc[rt] = __builtin_amdgcn_mfma_f32_16x16x32_bf16(af, bfv, acc[rt], 0, 0, 0);
    }
  }
  float psum = 0.f;
#pragma unroll
  for (int rt = 0; rt < 8; rt++) {
    float4 wf = *(const float4*)(Wfc + 16 * rt + 4 * lq);
    psum += wf.x * (0.1f * acc[rt][0] + 0.9f * bf2f(a1s[rt][0]));
    psum += wf.y * (0.1f * acc[rt][1] + 0.9f * bf2f(a1s[rt][1]));
    psum += wf.z * (0.1f * acc[rt][2] + 0.9f * bf2f(a1s[rt][2]));
    psum += wf.w * (0.1f * acc[rt][3] + 0.9f * bf2f(a1s[rt][3]));
  }
  psum += __shfl_xor(psum, 16);
  psum += __shfl_xor(psum, 32);
  if (lq == 0)
    out[b * 256 + nrow] = __builtin_amdgcn_rcpf(1.f + fexp2(-1.44269504f * psum));
}

// ---------------------------------------------------------------------------
extern "C" void kernel_launch(void* const* d_in, const int* in_sizes, int n_in,
                              void* d_out, int out_size, void* d_ws, size_t ws_size,
                              hipStream_t stream)
{
  const float* x    = (const float*)d_in[0];
  const float* A    = (const float*)d_in[1];
  const float* Wih0 = (const float*)d_in[2];
  const float* Whh0 = (const float*)d_in[3];
  const float* bih0 = (const float*)d_in[4];
  const float* bhh0 = (const float*)d_in[5];
  const float* Wih1 = (const float*)d_in[6];
  const float* Whh1 = (const float*)d_in[7];
  const float* bih1 = (const float*)d_in[8];
  const float* bhh1 = (const float*)d_in[9];
  const float* W1   = (const float*)d_in[10];
  const float* W2   = (const float*)d_in[11];
  const float* W3   = (const float*)d_in[12];
  const float* Wfc  = (const float*)d_in[13];
  char* ws = (char*)d_ws;

  prep_all<<<(PREPALL_TOT + 255) / 256, 256, 0, stream>>>(
      x, A, Wih0, Whh0, bih0, bhh0, Wih1, Whh1, bih1, bhh1, W1, W2, W3, ws);

  size_t need_full = (size_t)O_H1 + 134217728u;  // 8192-row h1
  size_t need_half = (size_t)O_H1 + 67108864u;   // 4096-row h1
  if (ws_size >= need_full) {
    lstm0_k<<<256, 1024, 0, stream>>>(ws, 0);
    lstm1_k<<<256, 1024, 0, stream>>>(ws, 0);
  } else if (ws_size >= need_half) {
    for (int c = 0; c < 2; c++) {
      lstm0_k<<<128, 1024, 0, stream>>>(ws, c * 4096);
      lstm1_k<<<128, 1024, 0, stream>>>(ws, c * 4096);
    }
  } else {
    for (int c = 0; c < 4; c++) {
      lstm0_k<<<64, 1024, 0, stream>>>(ws, c * 2048);
      lstm1_k<<<64, 1024, 0, stream>>>(ws, c * 2048);
    }
  }

  g_all<<<32, 1024, 0, stream>>>(ws, Wfc, (float*)d_out);
}

// Round 16
// 272.277 us; speedup vs baseline: 1.0331x; 1.0331x over previous
//
#include <hip/hip_runtime.h>

// ---------------------------------------------------------------------------
// 2-layer LSTM (BN=8192 seqs, T=64, F=16, H=128) + graph mixing stage.
// LSTM stage = round 13 exact (best verified: 260.8us).
// Round 16: graph stage = gA (fused P1..P3, column-local in n, grid 128 =
// 32b x 4 n-chunks, 64 cols/block, HA+mid in LDS) + g4 (P4, r13-exact).
// r15 lesson: full fusion at grid 32 starves the machine; this keeps grids
// wide and still kills the HAt/midT HBM round-trips + 2 launches.
// MFMA frag conventions (verified rounds 1-15):
//   A-frag: lane l holds A[16*rt + (l&15)][32*kt + 8*(l>>4) + i], i=0..7
//   B-frag: lane l holds B[32*kt + 8*(l>>4) + i][16*ct + (l&15)]
//   D:      lane l, reg r holds D[16*rt + 4*(l>>4) + r][16*ct + (l&15)]
// ---------------------------------------------------------------------------

typedef __attribute__((ext_vector_type(4))) float f32x4;
typedef __attribute__((ext_vector_type(2))) float f32x2;
typedef __attribute__((ext_vector_type(8))) __bf16 bf16x8;
typedef __attribute__((ext_vector_type(8))) unsigned short u16x8;
typedef __attribute__((ext_vector_type(4))) unsigned short u16x4;

#define DEV static __device__ __forceinline__

DEV unsigned short f2bf(float f) {
  unsigned u = __builtin_bit_cast(unsigned, f);
  u = u + 0x7fffu + ((u >> 16) & 1u);
  return (unsigned short)(u >> 16);
}
DEV float bf2f(unsigned short s) {
  unsigned u = ((unsigned)s) << 16;
  return __builtin_bit_cast(float, u);
}

DEV float fexp2(float x) { return __builtin_amdgcn_exp2f(x); }   // raw v_exp_f32
DEV f32x2 exp2v2(f32x2 x) { f32x2 r; r[0] = fexp2(x[0]); r[1] = fexp2(x[1]); return r; }
DEV f32x2 rcpv2(f32x2 x) {
  f32x2 r; r[0] = __builtin_amdgcn_rcpf(x[0]); r[1] = __builtin_amdgcn_rcpf(x[1]); return r;
}

// Two independent LSTM cells in packed f32x2 lanes; 5 exp2 + 2 rcp per cell.
// Gates PRE-SCALED: i,f,o by log2(e); g by 2*log2(e).  cs = 2*log2(e)*c.
DEV unsigned cell_pair(f32x2 gi, f32x2 gf, f32x2 gg, f32x2 go, f32x2& cs) {
  const float K2 = 2.88539008f;
  f32x2 one = {1.f, 1.f};
  f32x2 t1 = exp2v2(gg);                               // e^{2g}
  f32x2 t2 = exp2v2((f32x2){-gi[0], -gi[1]});          // e^{-i}
  f32x2 ef = exp2v2((f32x2){-gf[0], -gf[1]});          // e^{-f}
  f32x2 d1 = t1 + one;
  f32x2 den1 = d1 * t2 + d1;                           // (t1+1)(1+e^{-i})
  f32x2 e1 = one + ef;
  f32x2 num = cs * den1 + (f32x2){K2, K2} * (t1 - one) * e1;
  cs = num * rcpv2(e1 * den1);
  f32x2 t3 = exp2v2(cs);                               // e^{2c}
  f32x2 t4 = exp2v2((f32x2){-go[0], -go[1]});          // e^{-o}
  f32x2 d3 = t3 + one;
  f32x2 den3 = d3 * t4 + d3;
  f32x2 h = (t3 - one) * rcpv2(den3);                  // sig(o)*tanh(c)
  unsigned r;
  asm("v_cvt_pk_bf16_f32 %0, %1, %2" : "=v"(r) : "v"(h[0]), "v"(h[1]));
  return r;
}

// ---------------- workspace layout (bytes) ----------------
#define O_W0PK   0            // 163840
#define O_W1PK   163840       // 262144
#define O_APK    425984       // 131072
#define O_W1APK  557056       // 32768
#define O_W2APK  589824       // 32768
#define O_W3APK  622592       // 32768
#define O_BIAS0  655360       // 2048
#define O_BIAS1  657408       // 2048 (pre-scaled)
#define O_HTT    659456       // 2097152  hT^T [32][128][256] bf16
#define O_W1HAT  2756608      // 2097152  W1hA [b][n][g] bf16
#define O_W3R    4853760      // 2097152  W3r  [b][f][n] bf16
#define O_XPK    11145216     // 33554432 x B-frags (padded K=32, pad col16=1.0)
#define O_H1     44699648     // up to 128 MiB h1 [row][t][128] bf16

#define PREPX_TOT 2097152
#define PREP_TOT  328704
#define PREPALL_TOT (PREPX_TOT + PREP_TOT)

// unit for packed gate-row tile rt, lane-quad lq, within-pair s = rt&1
DEV int gr_unit(int rt, int lq2, int s) { return 8 * (rt >> 1) + 2 * lq2 + s; }

// ---------------- merged prepass: x frags + weight packs -------------------
__global__ void prep_all(const float* __restrict__ x, const float* __restrict__ A,
    const float* __restrict__ Wih0, const float* __restrict__ Whh0,
    const float* __restrict__ bih0, const float* __restrict__ bhh0,
    const float* __restrict__ Wih1, const float* __restrict__ Whh1,
    const float* __restrict__ bih1, const float* __restrict__ bhh1,
    const float* __restrict__ W1, const float* __restrict__ W2,
    const float* __restrict__ W3, char* __restrict__ ws)
{
  const float K1 = 1.44269504f, K2 = 2.88539008f;
  int gidx = blockIdx.x * blockDim.x + threadIdx.x;
  if (gidx < PREPX_TOT) {                  // x -> padded B-frag bf16
    int tid = gidx;
    int dat = (tid < 1048576) ? 1 : 0;
    int id = tid & 1048575;
    int half = id & 1, t = (id >> 1) & 63, row = id >> 7;
    u16x8 v = (u16x8)0;
    if (dat) {
      const float* p = x + ((long)row * 64 + t) * 16 + 8 * half;
      float4 a = *(const float4*)p;
      float4 b = *(const float4*)(p + 4);
      v[0] = f2bf(a.x); v[1] = f2bf(a.y); v[2] = f2bf(a.z); v[3] = f2bf(a.w);
      v[4] = f2bf(b.x); v[5] = f2bf(b.y); v[6] = f2bf(b.z); v[7] = f2bf(b.w);
    } else if (half == 0) {
      v[0] = 0x3F80;                            // k=16 -> 1.0f (bias column)
    }
    int lane = (dat ? 0 : 32) + half * 16 + (row & 15);
    int rt = row >> 4;
    ((u16x8*)(ws + O_XPK))[(rt * 64 + t) * 64 + lane] = v;
    return;
  }
  int idx = gidx - PREPX_TOT;
  if (idx >= PREP_TOT) return;
  if (idx < 81920) {                       // W0pk A-frags
    int o = idx, i = o & 7, l = (o >> 3) & 63, f = o >> 9;
    int kt = f % 5, rt = f / 5;
    int lr = l & 15, lq = l >> 4;
    int p = lr & 3, lql = (lr >> 2) & 3;
    int gc = p * 128 + gr_unit(rt, lql, rt & 1);
    float sc = (p == 2) ? K2 : K1;
    float v;
    if (kt < 4) v = Whh0[gc * 128 + 32 * kt + 8 * lq + i];
    else {
      int kk = 8 * lq + i;
      v = (kk < 16) ? Wih0[gc * 16 + kk]
                    : (kk == 16 ? (bih0[gc] + bhh0[gc]) : 0.f);  // bias row
    }
    ((unsigned short*)(ws + O_W0PK))[idx] = f2bf(v * sc);
  } else if (idx < 212992) {               // W1pk: kt<4 = h1-input, kt>=4 = recurrent
    int o = idx - 81920, i = o & 7, l = (o >> 3) & 63, f = o >> 9;
    int kt = f & 7, rt = f >> 3;
    int lr = l & 15, lq = l >> 4;
    int p = lr & 3, lql = (lr >> 2) & 3;
    int gc = p * 128 + gr_unit(rt, lql, rt & 1);
    float sc = (p == 2) ? K2 : K1;
    float v = (kt < 4) ? Wih1[gc * 128 + 32 * kt + 8 * lq + i]
                       : Whh1[gc * 128 + 32 * (kt - 4) + 8 * lq + i];
    ((unsigned short*)(ws + O_W1PK))[o] = f2bf(v * sc);
  } else if (idx < 278528) {               // Apk = sigmoid(A) B-frags
    int o = idx - 212992, i = o & 7, l = (o >> 3) & 63, f = o >> 9;
    int kt = f & 7, ct = f >> 3;
    int n = 32 * kt + 8 * (l >> 4) + i;
    int lc = 16 * ct + (l & 15);
    float e = fexp2(-K1 * A[n * 256 + lc]);
    ((unsigned short*)(ws + O_APK))[o] = f2bf(__builtin_amdgcn_rcpf(1.f + e));
  } else if (idx < 327680) {               // W1/W2/W3 A-frags (graph stage)
    int o = idx - 278528;
    int m = o >> 14;
    int oo = o & 16383;
    int i = oo & 7, l = (oo >> 3) & 63, f = oo >> 9;
    int kt = f & 3, rt = f >> 2;
    int g = 16 * rt + (l & 15);
    int k = 32 * kt + 8 * (l >> 4) + i;
    const float* W = (m == 0) ? W1 : (m == 1) ? W2 : W3;
    unsigned short* dst = (unsigned short*)(ws + ((m == 0) ? O_W1APK : (m == 1) ? O_W2APK : O_W3APK));
    dst[oo] = f2bf(W[g * 128 + k]);
  } else if (idx < 328192) {
    int c = idx - 327680;
    ((float*)(ws + O_BIAS0))[c] = bih0[c] + bhh0[c];
  } else {                                 // BIAS1: pre-scaled by gate
    int c = idx - 328192;
    float sc = ((c >> 7) == 2) ? K2 : K1;
    ((float*)(ws + O_BIAS1))[c] = (bih1[c] + bhh1[c]) * sc;
  }
}

// ---------------- LSTM layer 0: 32 rows/block, 16 waves (r13 exact) --------
__global__ __launch_bounds__(1024, 4) void lstm0_k(char* __restrict__ ws, int row_base)
{
  const unsigned short* W0pk = (const unsigned short*)(ws + O_W0PK);
  const unsigned short* xpk = (const unsigned short*)(ws + O_XPK);
  unsigned short* h1 = (unsigned short*)(ws + O_H1);

  int tid = threadIdx.x;
  int Wv = tid >> 6, l = tid & 63, lr = l & 15, lq = l >> 4;
  int lrow = blockIdx.x * 32;
  long grow0 = (long)row_base + lrow;

  __shared__ unsigned char hlds[2][8192];
  ((u16x8*)hlds[0])[tid] = (u16x8)0;

  bf16x8 Af[2][5];
#pragma unroll
  for (int s = 0; s < 2; s++)
#pragma unroll
    for (int kt = 0; kt < 5; kt++)
      Af[s][kt] = ((const bf16x8*)W0pk)[(((2 * Wv + s) * 5) + kt) * 64 + l];

  f32x2 c_st[2] = {{0.f, 0.f}, {0.f, 0.f}};

  int rd[2][4], whp[2];
#pragma unroll
  for (int ct = 0; ct < 2; ct++) {
#pragma unroll
    for (int kt = 0; kt < 4; kt++)
      rd[ct][kt] = (16 * ct + lr) * 256 + ((64 * kt + 16 * lq) ^ ((lr & 7) << 4));
    whp[ct] = (16 * ct + lr) * 256 + ((16 * Wv + 4 * lq) ^ ((lr & 7) << 4));
  }

  int pr = tid >> 6, sj = tid & 63;
  int sld0 = pr * 256 + ((4 * sj) ^ ((pr & 7) << 4));
  int sld1 = (pr + 16) * 256 + ((4 * sj) ^ ((pr & 7) << 4));
  unsigned short* st0 = h1 + (long)(lrow + pr) * 8192 + 2 * sj;
  unsigned short* st1 = h1 + (long)(lrow + pr + 16) * 8192 + 2 * sj;

  const bf16x8* xp0 = (const bf16x8*)xpk + ((grow0 >> 4) + 0) * 4096 + l;
  const bf16x8* xp1 = (const bf16x8*)xpk + ((grow0 >> 4) + 1) * 4096 + l;
  bf16x8 xb[2] = {xp0[0], xp1[0]};
  __syncthreads();

  for (int t = 0; t < 64; t++) {
    const unsigned char* rbuf = hlds[t & 1];
    unsigned char* wbuf = hlds[(t & 1) ^ 1];
    int tn = (t < 63) ? t + 1 : 63;
    bf16x8 xbn0 = xp0[tn * 64];
    bf16x8 xbn1 = xp1[tn * 64];

    f32x4 acc[2][2];
#pragma unroll
    for (int ct = 0; ct < 2; ct++)
#pragma unroll
      for (int s = 0; s < 2; s++) acc[ct][s] = (f32x4){0.f, 0.f, 0.f, 0.f};
    __builtin_amdgcn_s_setprio(1);
#pragma unroll
    for (int kt = 0; kt < 4; kt++) {
      bf16x8 hb0 = *(const bf16x8*)(rbuf + rd[0][kt]);
      bf16x8 hb1 = *(const bf16x8*)(rbuf + rd[1][kt]);
      acc[0][0] = __builtin_amdgcn_mfma_f32_16x16x32_bf16(Af[0][kt], hb0, acc[0][0], 0, 0, 0);
      acc[0][1] = __builtin_amdgcn_mfma_f32_16x16x32_bf16(Af[1][kt], hb0, acc[0][1], 0, 0, 0);
      acc[1][0] = __builtin_amdgcn_mfma_f32_16x16x32_bf16(Af[0][kt], hb1, acc[1][0], 0, 0, 0);
      acc[1][1] = __builtin_amdgcn_mfma_f32_16x16x32_bf16(Af[1][kt], hb1, acc[1][1], 0, 0, 0);
    }
    acc[0][0] = __builtin_amdgcn_mfma_f32_16x16x32_bf16(Af[0][4], xb[0], acc[0][0], 0, 0, 0);
    acc[0][1] = __builtin_amdgcn_mfma_f32_16x16x32_bf16(Af[1][4], xb[0], acc[0][1], 0, 0, 0);
    acc[1][0] = __builtin_amdgcn_mfma_f32_16x16x32_bf16(Af[0][4], xb[1], acc[1][0], 0, 0, 0);
    acc[1][1] = __builtin_amdgcn_mfma_f32_16x16x32_bf16(Af[1][4], xb[1], acc[1][1], 0, 0, 0);
    __builtin_amdgcn_s_setprio(0);
#pragma unroll
    for (int ct = 0; ct < 2; ct++) {
      f32x2 gi = {acc[ct][0][0], acc[ct][1][0]};
      f32x2 gf = {acc[ct][0][1], acc[ct][1][1]};
      f32x2 gg = {acc[ct][0][2], acc[ct][1][2]};
      f32x2 go = {acc[ct][0][3], acc[ct][1][3]};
      *(unsigned*)(wbuf + whp[ct]) = cell_pair(gi, gf, gg, go, c_st[ct]);
    }
    xb[0] = xbn0; xb[1] = xbn1;
    __syncthreads();
    *(unsigned*)(st0 + t * 128) = *(const unsigned*)(hlds[(t & 1) ^ 1] + sld0);
    *(unsigned*)(st1 + t * 128) = *(const unsigned*)(hlds[(t & 1) ^ 1] + sld1);
  }
}

// ---------------- LSTM layer 1: 32 rows/block, 16 waves (r13 exact) --------
__global__ __launch_bounds__(1024, 4) void lstm1_k(char* __restrict__ ws, int row_base)
{
  const unsigned short* W1pk = (const unsigned short*)(ws + O_W1PK);
  const float* bias1 = (const float*)(ws + O_BIAS1);
  const unsigned short* h1 = (const unsigned short*)(ws + O_H1);
  unsigned short* hTt = (unsigned short*)(ws + O_HTT);

  int tid = threadIdx.x;
  int Wv = tid >> 6, l = tid & 63, lr = l & 15, lq = l >> 4;
  int lrow = blockIdx.x * 32;
  long grow0 = (long)row_base + lrow;

  __shared__ unsigned char hlds[2][8192];
  __shared__ unsigned char h1s[2][8192];
  ((u16x8*)hlds[0])[tid] = (u16x8)0;

  int prow = tid >> 6, pc = tid & 63;
  const unsigned short* s0 = h1 + (long)(lrow + prow) * 8192 + 2 * pc;
  const unsigned short* s1 = h1 + (long)(lrow + prow + 16) * 8192 + 2 * pc;
  int d0 = prow * 256 + ((4 * pc) ^ ((prow & 7) << 4));
  int d1 = (prow + 16) * 256 + ((4 * pc) ^ ((prow & 7) << 4));
  *(unsigned*)(h1s[0] + d0) = *(const unsigned*)s0;
  *(unsigned*)(h1s[0] + d1) = *(const unsigned*)s1;

  bf16x8 Af[2][8];
#pragma unroll
  for (int s = 0; s < 2; s++)
#pragma unroll
    for (int kt = 0; kt < 8; kt++)
      Af[s][kt] = ((const bf16x8*)W1pk)[(((2 * Wv + s) * 8) + kt) * 64 + l];

  f32x4 bias_c[2];
#pragma unroll
  for (int s = 0; s < 2; s++)
#pragma unroll
    for (int r = 0; r < 4; r++)
      bias_c[s][r] = bias1[r * 128 + 8 * Wv + 2 * lq + s];

  f32x2 c_st[2] = {{0.f, 0.f}, {0.f, 0.f}};

  int rd[2][4], whp[2];
#pragma unroll
  for (int ct = 0; ct < 2; ct++) {
#pragma unroll
    for (int kt = 0; kt < 4; kt++)
      rd[ct][kt] = (16 * ct + lr) * 256 + ((64 * kt + 16 * lq) ^ ((lr & 7) << 4));
    whp[ct] = (16 * ct + lr) * 256 + ((16 * Wv + 4 * lq) ^ ((lr & 7) << 4));
  }
  __syncthreads();

  for (int t = 0; t < 64; t++) {
    const unsigned char* rbuf = hlds[t & 1];
    unsigned char* wbuf = hlds[(t & 1) ^ 1];
    const unsigned char* h1r = h1s[t & 1];
    unsigned char* h1w = h1s[(t & 1) ^ 1];
    int tn = (t < 63) ? t + 1 : 63;
    unsigned pf0 = *(const unsigned*)(s0 + tn * 128);
    unsigned pf1 = *(const unsigned*)(s1 + tn * 128);

    f32x4 acc[2][2];
#pragma unroll
    for (int ct = 0; ct < 2; ct++) {
      acc[ct][0] = bias_c[0]; acc[ct][1] = bias_c[1];
    }
    __builtin_amdgcn_s_setprio(1);
#pragma unroll
    for (int kt = 0; kt < 4; kt++) {
      bf16x8 xb0 = *(const bf16x8*)(h1r + rd[0][kt]);
      bf16x8 xb1 = *(const bf16x8*)(h1r + rd[1][kt]);
      acc[0][0] = __builtin_amdgcn_mfma_f32_16x16x32_bf16(Af[0][kt], xb0, acc[0][0], 0, 0, 0);
      acc[0][1] = __builtin_amdgcn_mfma_f32_16x16x32_bf16(Af[1][kt], xb0, acc[0][1], 0, 0, 0);
      acc[1][0] = __builtin_amdgcn_mfma_f32_16x16x32_bf16(Af[0][kt], xb1, acc[1][0], 0, 0, 0);
      acc[1][1] = __builtin_amdgcn_mfma_f32_16x16x32_bf16(Af[1][kt], xb1, acc[1][1], 0, 0, 0);
    }
#pragma unroll
    for (int kt = 0; kt < 4; kt++) {
      bf16x8 hb0 = *(const bf16x8*)(rbuf + rd[0][kt]);
      bf16x8 hb1 = *(const bf16x8*)(rbuf + rd[1][kt]);
      acc[0][0] = __builtin_amdgcn_mfma_f32_16x16x32_bf16(Af[0][4 + kt], hb0, acc[0][0], 0, 0, 0);
      acc[0][1] = __builtin_amdgcn_mfma_f32_16x16x32_bf16(Af[1][4 + kt], hb0, acc[0][1], 0, 0, 0);
      acc[1][0] = __builtin_amdgcn_mfma_f32_16x16x32_bf16(Af[0][4 + kt], hb1, acc[1][0], 0, 0, 0);
      acc[1][1] = __builtin_amdgcn_mfma_f32_16x16x32_bf16(Af[1][4 + kt], hb1, acc[1][1], 0, 0, 0);
    }
    __builtin_amdgcn_s_setprio(0);
#pragma unroll
    for (int ct = 0; ct < 2; ct++) {
      f32x2 gi = {acc[ct][0][0], acc[ct][1][0]};
      f32x2 gf = {acc[ct][0][1], acc[ct][1][1]};
      f32x2 gg = {acc[ct][0][2], acc[ct][1][2]};
      f32x2 go = {acc[ct][0][3], acc[ct][1][3]};
      *(unsigned*)(wbuf + whp[ct]) = cell_pair(gi, gf, gg, go, c_st[ct]);
    }
    *(unsigned*)(h1w + d0) = pf0;
    *(unsigned*)(h1w + d1) = pf1;
    __syncthreads();
  }

#pragma unroll
  for (int ct = 0; ct < 2; ct++) {
    unsigned hp = *(const unsigned*)(hlds[0] + whp[ct]);
    long grow = grow0 + 16 * ct + lr;
    long base = ((grow >> 8) * 128) * 256 + (grow & 255);
    int u0 = 8 * Wv + 2 * lq;
    hTt[base + (long)u0 * 256] = (unsigned short)(hp & 0xffff);
    hTt[base + (long)(u0 + 1) * 256] = (unsigned short)(hp >> 16);
  }
}

// ---------------- gA: fused P1..P3, column-local (grid 32b x 4 n-chunks) ---
// P1: HA = hTt_b @ Apk -> lA [64 cols][128 h] swz8
// P2: W1hA -> global [b][n][g]; mid = relu(W2@HA) -> lB
// P3: W3r = W3@mid -> global [b][f][n]
__global__ __launch_bounds__(256, 4) void gA_kernel(char* __restrict__ ws)
{
  const unsigned short* hTt = (const unsigned short*)(ws + O_HTT);
  const unsigned short* Apk = (const unsigned short*)(ws + O_APK);
  const unsigned short* W1apk = (const unsigned short*)(ws + O_W1APK);
  const unsigned short* W2apk = (const unsigned short*)(ws + O_W2APK);
  const unsigned short* W3apk = (const unsigned short*)(ws + O_W3APK);
  unsigned short* W1hAt = (unsigned short*)(ws + O_W1HAT);
  unsigned short* W3r = (unsigned short*)(ws + O_W3R);

  __shared__ unsigned char lA[16384];
  __shared__ unsigned char lB[16384];

  int tid = threadIdx.x;
  int w = tid >> 6, l = tid & 63, lr = l & 15, lq = l >> 4;
  int bi = blockIdx.x;
  int b = bi >> 2, nc = bi & 3;
  int ctg = nc * 4 + w;                        // global 16-col tile (0..15)
  int nloc = 16 * w + lr;                      // local col (0..63)
  int nglob = 16 * ctg + lr;                   // global col (0..255)

  // ---- P1 ----
  f32x4 acc[8];
#pragma unroll
  for (int rt = 0; rt < 8; rt++) acc[rt] = (f32x4){0.f, 0.f, 0.f, 0.f};
  for (int kt = 0; kt < 8; kt++) {
    bf16x8 bfv = ((const bf16x8*)Apk)[(ctg * 8 + kt) * 64 + l];
#pragma unroll
    for (int rt = 0; rt < 8; rt++) {
      bf16x8 af = *(const bf16x8*)(hTt + (long)(b * 128 + 16 * rt + lr) * 256 + 32 * kt + 8 * lq);
      acc[rt] = __builtin_amdgcn_mfma_f32_16x16x32_bf16(af, bfv, acc[rt], 0, 0, 0);
    }
  }
#pragma unroll
  for (int rt = 0; rt < 8; rt++) {
    u16x4 pk;
#pragma unroll
    for (int r = 0; r < 4; r++) pk[r] = f2bf(acc[rt][r]);
    *(u16x4*)(lA + nloc * 256 + ((32 * rt + 8 * lq) ^ ((lr & 7) << 4))) = pk;
  }
  __syncthreads();

  // ---- P2 ----
  int rdH[4];
#pragma unroll
  for (int kt = 0; kt < 4; kt++)
    rdH[kt] = nloc * 256 + ((64 * kt + 16 * lq) ^ ((lr & 7) << 4));

  f32x4 a2[8];
#pragma unroll
  for (int rt = 0; rt < 8; rt++) { acc[rt] = (f32x4){0.f,0.f,0.f,0.f}; a2[rt] = (f32x4){0.f,0.f,0.f,0.f}; }
  for (int kt = 0; kt < 4; kt++) {
    bf16x8 bfv = *(const bf16x8*)(lA + rdH[kt]);
#pragma unroll
    for (int rt = 0; rt < 8; rt++) {
      bf16x8 af1 = ((const bf16x8*)W1apk)[(rt * 4 + kt) * 64 + l];
      bf16x8 af2 = ((const bf16x8*)W2apk)[(rt * 4 + kt) * 64 + l];
      acc[rt] = __builtin_amdgcn_mfma_f32_16x16x32_bf16(af1, bfv, acc[rt], 0, 0, 0);
      a2[rt]  = __builtin_amdgcn_mfma_f32_16x16x32_bf16(af2, bfv, a2[rt], 0, 0, 0);
    }
  }
#pragma unroll
  for (int rt = 0; rt < 8; rt++) {
    u16x4 p1, p2;
#pragma unroll
    for (int r = 0; r < 4; r++) {
      p1[r] = f2bf(acc[rt][r]);
      p2[r] = f2bf(fmaxf(a2[rt][r], 0.f));
    }
    *(u16x4*)(W1hAt + (long)(b * 256 + nglob) * 128 + 16 * rt + 4 * lq) = p1;
    *(u16x4*)(lB + nloc * 256 + ((32 * rt + 8 * lq) ^ ((lr & 7) << 4))) = p2;
  }
  __syncthreads();

  // ---- P3 ----
#pragma unroll
  for (int rt = 0; rt < 8; rt++) acc[rt] = (f32x4){0.f, 0.f, 0.f, 0.f};
  for (int kt = 0; kt < 4; kt++) {
    bf16x8 bfv = *(const bf16x8*)(lB + rdH[kt]);
#pragma unroll
    for (int rt = 0; rt < 8; rt++) {
      bf16x8 af3 = ((const bf16x8*)W3apk)[(rt * 4 + kt) * 64 + l];
      acc[rt] = __builtin_amdgcn_mfma_f32_16x16x32_bf16(af3, bfv, acc[rt], 0, 0, 0);
    }
  }
#pragma unroll
  for (int rt = 0; rt < 8; rt++)
#pragma unroll
    for (int r = 0; r < 4; r++)
      W3r[(long)(b * 128 + 16 * rt + 4 * lq + r) * 256 + nglob] = f2bf(acc[rt][r]);
}

// ---------------- g4: P4 (r13 exact) ---------------------------------------
__global__ __launch_bounds__(256, 2) void g4_kernel(char* __restrict__ ws,
    const float* __restrict__ Wfc, float* __restrict__ out)
{
  const unsigned short* W3r = (const unsigned short*)(ws + O_W3R);
  const unsigned short* Apk = (const unsigned short*)(ws + O_APK);
  const unsigned short* W1hAt = (const unsigned short*)(ws + O_W1HAT);
  int tid = threadIdx.x, w = tid >> 6, l = tid & 63, lr = l & 15, lq = l >> 4;
  int bi = blockIdx.x;
  int b = bi >> 2, cq = bi & 3;
  int ct = cq * 4 + w;
  f32x4 acc[8];
#pragma unroll
  for (int i = 0; i < 8; i++) acc[i] = (f32x4){0.f, 0.f, 0.f, 0.f};
  for (int kt = 0; kt < 8; kt++) {
    bf16x8 bfv = ((const bf16x8*)Apk)[(ct * 8 + kt) * 64 + l];
#pragma unroll
    for (int rt = 0; rt < 8; rt++) {
      bf16x8 af = *(const bf16x8*)(W3r + (long)(b * 128 + 16 * rt + lr) * 256 + 32 * kt + 8 * lq);
      acc[rt] = __builtin_amdgcn_mfma_f32_16x16x32_bf16(af, bfv, acc[rt], 0, 0, 0);
    }
  }
  float psum = 0.f;
#pragma unroll
  for (int rt = 0; rt < 8; rt++) {
    float4 wf = *(const float4*)(Wfc + 16 * rt + 4 * lq);
    u16x4 wv = *(const u16x4*)(W1hAt + (long)(b * 256 + 16 * ct + lr) * 128 + 16 * rt + 4 * lq);
    psum += wf.x * (0.1f * acc[rt][0] + 0.9f * bf2f(wv[0]));
    psum += wf.y * (0.1f * acc[rt][1] + 0.9f * bf2f(wv[1]));
    psum += wf.z * (0.1f * acc[rt][2] + 0.9f * bf2f(wv[2]));
    psum += wf.w * (0.1f * acc[rt][3] + 0.9f * bf2f(wv[3]));
  }
  psum += __shfl_xor(psum, 16);
  psum += __shfl_xor(psum, 32);
  if (lq == 0) out[b * 256 + ct * 16 + lr] = __builtin_amdgcn_rcpf(1.f + fexp2(-1.44269504f * psum));
}

// ---------------------------------------------------------------------------
extern "C" void kernel_launch(void* const* d_in, const int* in_sizes, int n_in,
                              void* d_out, int out_size, void* d_ws, size_t ws_size,
                              hipStream_t stream)
{
  const float* x    = (const float*)d_in[0];
  const float* A    = (const float*)d_in[1];
  const float* Wih0 = (const float*)d_in[2];
  const float* Whh0 = (const float*)d_in[3];
  const float* bih0 = (const float*)d_in[4];
  const float* bhh0 = (const float*)d_in[5];
  const float* Wih1 = (const float*)d_in[6];
  const float* Whh1 = (const float*)d_in[7];
  const float* bih1 = (const float*)d_in[8];
  const float* bhh1 = (const float*)d_in[9];
  const float* W1   = (const float*)d_in[10];
  const float* W2   = (const float*)d_in[11];
  const float* W3   = (const float*)d_in[12];
  const float* Wfc  = (const float*)d_in[13];
  char* ws = (char*)d_ws;

  prep_all<<<(PREPALL_TOT + 255) / 256, 256, 0, stream>>>(
      x, A, Wih0, Whh0, bih0, bhh0, Wih1, Whh1, bih1, bhh1, W1, W2, W3, ws);

  size_t need_full = (size_t)O_H1 + 134217728u;  // 8192-row h1
  size_t need_half = (size_t)O_H1 + 67108864u;   // 4096-row h1
  if (ws_size >= need_full) {
    lstm0_k<<<256, 1024, 0, stream>>>(ws, 0);
    lstm1_k<<<256, 1024, 0, stream>>>(ws, 0);
  } else if (ws_size >= need_half) {
    for (int c = 0; c < 2; c++) {
      lstm0_k<<<128, 1024, 0, stream>>>(ws, c * 4096);
      lstm1_k<<<128, 1024, 0, stream>>>(ws, c * 4096);
    }
  } else {
    for (int c = 0; c < 4; c++) {
      lstm0_k<<<64, 1024, 0, stream>>>(ws, c * 2048);
      lstm1_k<<<64, 1024, 0, stream>>>(ws, c * 2048);
    }
  }

  gA_kernel<<<128, 256, 0, stream>>>(ws);
  g4_kernel<<<128, 256, 0, stream>>>(ws, Wfc, (float*)d_out);
}

// Round 17
// 260.247 us; speedup vs baseline: 1.0808x; 1.0462x over previous
//
#include <hip/hip_runtime.h>

// ---------------------------------------------------------------------------
// 2-layer LSTM (BN=8192 seqs, T=64, F=16, H=128) + graph mixing stage.
// FINAL: round-13 configuration (best verified: 260.8us).
// LSTM: 16x16x32 MFMA, 32 rows/block, 16 waves, (1024,4), T5 setprio,
// XOR-swizzled LDS h-state, coalesced h1 bounce, 5exp+2rcp cell (common-
// denominator algebra), weights/bias pre-scaled by log2e in prepass.
// Graph stage: four small wide-grid kernels g1..g4 (launch-pipelined; fusion
// variants r15/r16 both regressed).
// Issue-bound model closes at 97%: per step/SIMD = MFMA-issue 2484 cyc +
// trans-issue ~1790 + arith ~500 ~= measured 4926. MFMA count = algorithm
// FLOPs; 5 exp/cell is the LSTM minimum. Remaining headroom ~3%.
// MFMA frag conventions (verified rounds 1-13):
//   A-frag: lane l holds A[16*rt + (l&15)][32*kt + 8*(l>>4) + i], i=0..7
//   B-frag: lane l holds B[32*kt + 8*(l>>4) + i][16*ct + (l&15)]
//   D:      lane l, reg r holds D[16*rt + 4*(l>>4) + r][16*ct + (l&15)]
// ---------------------------------------------------------------------------

typedef __attribute__((ext_vector_type(4))) float f32x4;
typedef __attribute__((ext_vector_type(2))) float f32x2;
typedef __attribute__((ext_vector_type(8))) __bf16 bf16x8;
typedef __attribute__((ext_vector_type(8))) unsigned short u16x8;
typedef __attribute__((ext_vector_type(4))) unsigned short u16x4;

#define DEV static __device__ __forceinline__

DEV unsigned short f2bf(float f) {
  unsigned u = __builtin_bit_cast(unsigned, f);
  u = u + 0x7fffu + ((u >> 16) & 1u);
  return (unsigned short)(u >> 16);
}
DEV float bf2f(unsigned short s) {
  unsigned u = ((unsigned)s) << 16;
  return __builtin_bit_cast(float, u);
}

DEV float fexp2(float x) { return __builtin_amdgcn_exp2f(x); }   // raw v_exp_f32
DEV f32x2 exp2v2(f32x2 x) { f32x2 r; r[0] = fexp2(x[0]); r[1] = fexp2(x[1]); return r; }
DEV f32x2 rcpv2(f32x2 x) {
  f32x2 r; r[0] = __builtin_amdgcn_rcpf(x[0]); r[1] = __builtin_amdgcn_rcpf(x[1]); return r;
}

// Two independent LSTM cells in packed f32x2 lanes; 5 exp2 + 2 rcp per cell.
// Gates PRE-SCALED: i,f,o by log2(e); g by 2*log2(e).  cs = 2*log2(e)*c.
// cs' = cs*sig(f) + K2*sig(i)*tanh(g)
//     = (cs*den1 + K2*(t1-1)*(1+ef)) / ((1+ef)*den1),  den1=(t1+1)(1+t2)
DEV unsigned cell_pair(f32x2 gi, f32x2 gf, f32x2 gg, f32x2 go, f32x2& cs) {
  const float K2 = 2.88539008f;
  f32x2 one = {1.f, 1.f};
  f32x2 t1 = exp2v2(gg);                               // e^{2g}
  f32x2 t2 = exp2v2((f32x2){-gi[0], -gi[1]});          // e^{-i}
  f32x2 ef = exp2v2((f32x2){-gf[0], -gf[1]});          // e^{-f}
  f32x2 d1 = t1 + one;
  f32x2 den1 = d1 * t2 + d1;                           // (t1+1)(1+e^{-i})
  f32x2 e1 = one + ef;
  f32x2 num = cs * den1 + (f32x2){K2, K2} * (t1 - one) * e1;
  cs = num * rcpv2(e1 * den1);
  f32x2 t3 = exp2v2(cs);                               // e^{2c}
  f32x2 t4 = exp2v2((f32x2){-go[0], -go[1]});          // e^{-o}
  f32x2 d3 = t3 + one;
  f32x2 den3 = d3 * t4 + d3;
  f32x2 h = (t3 - one) * rcpv2(den3);                  // sig(o)*tanh(c)
  unsigned r;
  asm("v_cvt_pk_bf16_f32 %0, %1, %2" : "=v"(r) : "v"(h[0]), "v"(h[1]));
  return r;
}

// ---------------- workspace layout (bytes) ----------------
#define O_W0PK   0            // 32rt*5kt*64l*8i bf16 = 163840
#define O_W1PK   163840       // 32rt*8kt*64l*8i bf16 = 262144
#define O_APK    425984       // 131072
#define O_W1APK  557056       // 32768
#define O_W2APK  589824       // 32768
#define O_W3APK  622592       // 32768
#define O_BIAS0  655360       // 2048
#define O_BIAS1  657408       // 2048 (pre-scaled)
#define O_HTT    659456       // 2097152  hT^T [32][128][256] bf16
#define O_HAT    2756608      // 2097152
#define O_MIDT   4853760      // 2097152
#define O_W1HAT  6950912      // 2097152
#define O_W3R    9048064      // 2097152
#define O_XPK    11145216     // 33554432 x B-frags (padded K=32, pad col16=1.0)
#define O_H1     44699648     // up to 128 MiB h1 [row][t][128] bf16

#define PREPX_TOT 2097152
#define PREP_TOT  328704
#define PREPALL_TOT (PREPX_TOT + PREP_TOT)

// unit for packed gate-row tile rt, lane-quad lq, within-pair s = rt&1
DEV int gr_unit(int rt, int lq2, int s) { return 8 * (rt >> 1) + 2 * lq2 + s; }

// ---------------- merged prepass: x frags + weight packs -------------------
__global__ void prep_all(const float* __restrict__ x, const float* __restrict__ A,
    const float* __restrict__ Wih0, const float* __restrict__ Whh0,
    const float* __restrict__ bih0, const float* __restrict__ bhh0,
    const float* __restrict__ Wih1, const float* __restrict__ Whh1,
    const float* __restrict__ bih1, const float* __restrict__ bhh1,
    const float* __restrict__ W1, const float* __restrict__ W2,
    const float* __restrict__ W3, char* __restrict__ ws)
{
  const float K1 = 1.44269504f, K2 = 2.88539008f;
  int gidx = blockIdx.x * blockDim.x + threadIdx.x;
  if (gidx < PREPX_TOT) {                  // x -> padded B-frag bf16
    int tid = gidx;
    int dat = (tid < 1048576) ? 1 : 0;
    int id = tid & 1048575;
    int half = id & 1, t = (id >> 1) & 63, row = id >> 7;
    u16x8 v = (u16x8)0;
    if (dat) {
      const float* p = x + ((long)row * 64 + t) * 16 + 8 * half;
      float4 a = *(const float4*)p;
      float4 b = *(const float4*)(p + 4);
      v[0] = f2bf(a.x); v[1] = f2bf(a.y); v[2] = f2bf(a.z); v[3] = f2bf(a.w);
      v[4] = f2bf(b.x); v[5] = f2bf(b.y); v[6] = f2bf(b.z); v[7] = f2bf(b.w);
    } else if (half == 0) {
      v[0] = 0x3F80;                            // k=16 -> 1.0f (bias column)
    }
    int lane = (dat ? 0 : 32) + half * 16 + (row & 15);
    int rt = row >> 4;
    ((u16x8*)(ws + O_XPK))[(rt * 64 + t) * 64 + lane] = v;
    return;
  }
  int idx = gidx - PREPX_TOT;
  if (idx >= PREP_TOT) return;
  if (idx < 81920) {                       // W0pk A-frags
    int o = idx, i = o & 7, l = (o >> 3) & 63, f = o >> 9;
    int kt = f % 5, rt = f / 5;
    int lr = l & 15, lq = l >> 4;
    int p = lr & 3, lql = (lr >> 2) & 3;
    int gc = p * 128 + gr_unit(rt, lql, rt & 1);
    float sc = (p == 2) ? K2 : K1;
    float v;
    if (kt < 4) v = Whh0[gc * 128 + 32 * kt + 8 * lq + i];
    else {
      int kk = 8 * lq + i;
      v = (kk < 16) ? Wih0[gc * 16 + kk]
                    : (kk == 16 ? (bih0[gc] + bhh0[gc]) : 0.f);  // bias row
    }
    ((unsigned short*)(ws + O_W0PK))[idx] = f2bf(v * sc);
  } else if (idx < 212992) {               // W1pk: kt<4 = h1-input, kt>=4 = recurrent
    int o = idx - 81920, i = o & 7, l = (o >> 3) & 63, f = o >> 9;
    int kt = f & 7, rt = f >> 3;
    int lr = l & 15, lq = l >> 4;
    int p = lr & 3, lql = (lr >> 2) & 3;
    int gc = p * 128 + gr_unit(rt, lql, rt & 1);
    float sc = (p == 2) ? K2 : K1;
    float v = (kt < 4) ? Wih1[gc * 128 + 32 * kt + 8 * lq + i]
                       : Whh1[gc * 128 + 32 * (kt - 4) + 8 * lq + i];
    ((unsigned short*)(ws + O_W1PK))[o] = f2bf(v * sc);
  } else if (idx < 278528) {               // Apk = sigmoid(A) B-frags
    int o = idx - 212992, i = o & 7, l = (o >> 3) & 63, f = o >> 9;
    int kt = f & 7, ct = f >> 3;
    int n = 32 * kt + 8 * (l >> 4) + i;
    int lc = 16 * ct + (l & 15);
    float e = fexp2(-K1 * A[n * 256 + lc]);
    ((unsigned short*)(ws + O_APK))[o] = f2bf(__builtin_amdgcn_rcpf(1.f + e));
  } else if (idx < 327680) {               // W1/W2/W3 A-frags (graph stage)
    int o = idx - 278528;
    int m = o >> 14;
    int oo = o & 16383;
    int i = oo & 7, l = (oo >> 3) & 63, f = oo >> 9;
    int kt = f & 3, rt = f >> 2;
    int g = 16 * rt + (l & 15);
    int k = 32 * kt + 8 * (l >> 4) + i;
    const float* W = (m == 0) ? W1 : (m == 1) ? W2 : W3;
    unsigned short* dst = (unsigned short*)(ws + ((m == 0) ? O_W1APK : (m == 1) ? O_W2APK : O_W3APK));
    dst[oo] = f2bf(W[g * 128 + k]);
  } else if (idx < 328192) {
    int c = idx - 327680;
    ((float*)(ws + O_BIAS0))[c] = bih0[c] + bhh0[c];
  } else {                                 // BIAS1: pre-scaled by gate
    int c = idx - 328192;
    float sc = ((c >> 7) == 2) ? K2 : K1;
    ((float*)(ws + O_BIAS1))[c] = (bih1[c] + bhh1[c]) * sc;
  }
}

// ---------------- LSTM layer 0: 32 rows/block, 16 waves, 1 barrier/step ----
__global__ __launch_bounds__(1024, 4) void lstm0_k(char* __restrict__ ws, int row_base)
{
  const unsigned short* W0pk = (const unsigned short*)(ws + O_W0PK);
  const unsigned short* xpk = (const unsigned short*)(ws + O_XPK);
  unsigned short* h1 = (unsigned short*)(ws + O_H1);

  int tid = threadIdx.x;
  int Wv = tid >> 6, l = tid & 63, lr = l & 15, lq = l >> 4;
  int lrow = blockIdx.x * 32;
  long grow0 = (long)row_base + lrow;

  __shared__ unsigned char hlds[2][8192];  // h state [32 rows][128 u] swizzled
  ((u16x8*)hlds[0])[tid] = (u16x8)0;       // zero both buffers (16 KB)

  bf16x8 Af[2][5];                          // A-tiles rt = 2Wv+s
#pragma unroll
  for (int s = 0; s < 2; s++)
#pragma unroll
    for (int kt = 0; kt < 5; kt++)
      Af[s][kt] = ((const bf16x8*)W0pk)[(((2 * Wv + s) * 5) + kt) * 64 + l];

  f32x2 c_st[2] = {{0.f, 0.f}, {0.f, 0.f}};  // [ct], lanes = s

  int rd[2][4], whp[2];
#pragma unroll
  for (int ct = 0; ct < 2; ct++) {
#pragma unroll
    for (int kt = 0; kt < 4; kt++)
      rd[ct][kt] = (16 * ct + lr) * 256 + ((64 * kt + 16 * lq) ^ ((lr & 7) << 4));
    whp[ct] = (16 * ct + lr) * 256 + ((16 * Wv + 4 * lq) ^ ((lr & 7) << 4));
  }

  // coalesced h1 bounce: thread -> rows pr, pr+16, u32 col sj
  int pr = tid >> 6, sj = tid & 63;
  int sld0 = pr * 256 + ((4 * sj) ^ ((pr & 7) << 4));
  int sld1 = (pr + 16) * 256 + ((4 * sj) ^ ((pr & 7) << 4));
  unsigned short* st0 = h1 + (long)(lrow + pr) * 8192 + 2 * sj;
  unsigned short* st1 = h1 + (long)(lrow + pr + 16) * 8192 + 2 * sj;

  const bf16x8* xp0 = (const bf16x8*)xpk + ((grow0 >> 4) + 0) * 4096 + l;
  const bf16x8* xp1 = (const bf16x8*)xpk + ((grow0 >> 4) + 1) * 4096 + l;
  bf16x8 xb[2] = {xp0[0], xp1[0]};
  __syncthreads();

  for (int t = 0; t < 64; t++) {
    const unsigned char* rbuf = hlds[t & 1];
    unsigned char* wbuf = hlds[(t & 1) ^ 1];
    int tn = (t < 63) ? t + 1 : 63;          // branchless prefetch index
    bf16x8 xbn0 = xp0[tn * 64];
    bf16x8 xbn1 = xp1[tn * 64];

    f32x4 acc[2][2];
#pragma unroll
    for (int ct = 0; ct < 2; ct++)
#pragma unroll
      for (int s = 0; s < 2; s++) acc[ct][s] = (f32x4){0.f, 0.f, 0.f, 0.f};
    __builtin_amdgcn_s_setprio(1);           // T5: favor MFMA-issuing wave
#pragma unroll
    for (int kt = 0; kt < 4; kt++) {
      bf16x8 hb0 = *(const bf16x8*)(rbuf + rd[0][kt]);
      bf16x8 hb1 = *(const bf16x8*)(rbuf + rd[1][kt]);
      acc[0][0] = __builtin_amdgcn_mfma_f32_16x16x32_bf16(Af[0][kt], hb0, acc[0][0], 0, 0, 0);
      acc[0][1] = __builtin_amdgcn_mfma_f32_16x16x32_bf16(Af[1][kt], hb0, acc[0][1], 0, 0, 0);
      acc[1][0] = __builtin_amdgcn_mfma_f32_16x16x32_bf16(Af[0][kt], hb1, acc[1][0], 0, 0, 0);
      acc[1][1] = __builtin_amdgcn_mfma_f32_16x16x32_bf16(Af[1][kt], hb1, acc[1][1], 0, 0, 0);
    }
    acc[0][0] = __builtin_amdgcn_mfma_f32_16x16x32_bf16(Af[0][4], xb[0], acc[0][0], 0, 0, 0);
    acc[0][1] = __builtin_amdgcn_mfma_f32_16x16x32_bf16(Af[1][4], xb[0], acc[0][1], 0, 0, 0);
    acc[1][0] = __builtin_amdgcn_mfma_f32_16x16x32_bf16(Af[0][4], xb[1], acc[1][0], 0, 0, 0);
    acc[1][1] = __builtin_amdgcn_mfma_f32_16x16x32_bf16(Af[1][4], xb[1], acc[1][1], 0, 0, 0);
    __builtin_amdgcn_s_setprio(0);
#pragma unroll
    for (int ct = 0; ct < 2; ct++) {
      f32x2 gi = {acc[ct][0][0], acc[ct][1][0]};
      f32x2 gf = {acc[ct][0][1], acc[ct][1][1]};
      f32x2 gg = {acc[ct][0][2], acc[ct][1][2]};
      f32x2 go = {acc[ct][0][3], acc[ct][1][3]};
      *(unsigned*)(wbuf + whp[ct]) = cell_pair(gi, gf, gg, go, c_st[ct]);
    }
    xb[0] = xbn0; xb[1] = xbn1;
    __syncthreads();
    // h(t) complete in wbuf: coalesced global store (256B contiguous per wave)
    *(unsigned*)(st0 + t * 128) = *(const unsigned*)(hlds[(t & 1) ^ 1] + sld0);
    *(unsigned*)(st1 + t * 128) = *(const unsigned*)(hlds[(t & 1) ^ 1] + sld1);
  }
}

// ---------------- LSTM layer 1: 32 rows/block, 16 waves --------------------
__global__ __launch_bounds__(1024, 4) void lstm1_k(char* __restrict__ ws, int row_base)
{
  const unsigned short* W1pk = (const unsigned short*)(ws + O_W1PK);
  const float* bias1 = (const float*)(ws + O_BIAS1);
  const unsigned short* h1 = (const unsigned short*)(ws + O_H1);
  unsigned short* hTt = (unsigned short*)(ws + O_HTT);

  int tid = threadIdx.x;
  int Wv = tid >> 6, l = tid & 63, lr = l & 15, lq = l >> 4;
  int lrow = blockIdx.x * 32;
  long grow0 = (long)row_base + lrow;

  __shared__ unsigned char hlds[2][8192];  // layer-1 h state
  __shared__ unsigned char h1s[2][8192];   // staged h1 input
  ((u16x8*)hlds[0])[tid] = (u16x8)0;

  // h1 staging: thread -> rows prow, prow+16, u32 col pc
  int prow = tid >> 6, pc = tid & 63;
  const unsigned short* s0 = h1 + (long)(lrow + prow) * 8192 + 2 * pc;
  const unsigned short* s1 = h1 + (long)(lrow + prow + 16) * 8192 + 2 * pc;
  int d0 = prow * 256 + ((4 * pc) ^ ((prow & 7) << 4));
  int d1 = (prow + 16) * 256 + ((4 * pc) ^ ((prow & 7) << 4));
  *(unsigned*)(h1s[0] + d0) = *(const unsigned*)s0;   // t = 0
  *(unsigned*)(h1s[0] + d1) = *(const unsigned*)s1;

  bf16x8 Af[2][8];
#pragma unroll
  for (int s = 0; s < 2; s++)
#pragma unroll
    for (int kt = 0; kt < 8; kt++)
      Af[s][kt] = ((const bf16x8*)W1pk)[(((2 * Wv + s) * 8) + kt) * 64 + l];

  f32x4 bias_c[2];
#pragma unroll
  for (int s = 0; s < 2; s++)
#pragma unroll
    for (int r = 0; r < 4; r++)
      bias_c[s][r] = bias1[r * 128 + 8 * Wv + 2 * lq + s];

  f32x2 c_st[2] = {{0.f, 0.f}, {0.f, 0.f}};

  int rd[2][4], whp[2];
#pragma unroll
  for (int ct = 0; ct < 2; ct++) {
#pragma unroll
    for (int kt = 0; kt < 4; kt++)
      rd[ct][kt] = (16 * ct + lr) * 256 + ((64 * kt + 16 * lq) ^ ((lr & 7) << 4));
    whp[ct] = (16 * ct + lr) * 256 + ((16 * Wv + 4 * lq) ^ ((lr & 7) << 4));
  }
  __syncthreads();

  for (int t = 0; t < 64; t++) {
    const unsigned char* rbuf = hlds[t & 1];
    unsigned char* wbuf = hlds[(t & 1) ^ 1];
    const unsigned char* h1r = h1s[t & 1];
    unsigned char* h1w = h1s[(t & 1) ^ 1];
    int tn = (t < 63) ? t + 1 : 63;
    unsigned pf0 = *(const unsigned*)(s0 + tn * 128);
    unsigned pf1 = *(const unsigned*)(s1 + tn * 128);

    f32x4 acc[2][2];
#pragma unroll
    for (int ct = 0; ct < 2; ct++) {
      acc[ct][0] = bias_c[0]; acc[ct][1] = bias_c[1];
    }
    __builtin_amdgcn_s_setprio(1);           // T5
#pragma unroll
    for (int kt = 0; kt < 4; kt++) {
      bf16x8 xb0 = *(const bf16x8*)(h1r + rd[0][kt]);
      bf16x8 xb1 = *(const bf16x8*)(h1r + rd[1][kt]);
      acc[0][0] = __builtin_amdgcn_mfma_f32_16x16x32_bf16(Af[0][kt], xb0, acc[0][0], 0, 0, 0);
      acc[0][1] = __builtin_amdgcn_mfma_f32_16x16x32_bf16(Af[1][kt], xb0, acc[0][1], 0, 0, 0);
      acc[1][0] = __builtin_amdgcn_mfma_f32_16x16x32_bf16(Af[0][kt], xb1, acc[1][0], 0, 0, 0);
      acc[1][1] = __builtin_amdgcn_mfma_f32_16x16x32_bf16(Af[1][kt], xb1, acc[1][1], 0, 0, 0);
    }
#pragma unroll
    for (int kt = 0; kt < 4; kt++) {
      bf16x8 hb0 = *(const bf16x8*)(rbuf + rd[0][kt]);
      bf16x8 hb1 = *(const bf16x8*)(rbuf + rd[1][kt]);
      acc[0][0] = __builtin_amdgcn_mfma_f32_16x16x32_bf16(Af[0][4 + kt], hb0, acc[0][0], 0, 0, 0);
      acc[0][1] = __builtin_amdgcn_mfma_f32_16x16x32_bf16(Af[1][4 + kt], hb0, acc[0][1], 0, 0, 0);
      acc[1][0] = __builtin_amdgcn_mfma_f32_16x16x32_bf16(Af[0][4 + kt], hb1, acc[1][0], 0, 0, 0);
      acc[1][1] = __builtin_amdgcn_mfma_f32_16x16x32_bf16(Af[1][4 + kt], hb1, acc[1][1], 0, 0, 0);
    }
    __builtin_amdgcn_s_setprio(0);
#pragma unroll
    for (int ct = 0; ct < 2; ct++) {
      f32x2 gi = {acc[ct][0][0], acc[ct][1][0]};
      f32x2 gf = {acc[ct][0][1], acc[ct][1][1]};
      f32x2 gg = {acc[ct][0][2], acc[ct][1][2]};
      f32x2 go = {acc[ct][0][3], acc[ct][1][3]};
      *(unsigned*)(wbuf + whp[ct]) = cell_pair(gi, gf, gg, go, c_st[ct]);
    }
    *(unsigned*)(h1w + d0) = pf0;
    *(unsigned*)(h1w + d1) = pf1;
    __syncthreads();
  }

  // peeled epilogue: final h (t=63) lives in hlds[0]; scatter to hTt [b][u][n]
#pragma unroll
  for (int ct = 0; ct < 2; ct++) {
    unsigned hp = *(const unsigned*)(hlds[0] + whp[ct]);
    long grow = grow0 + 16 * ct + lr;
    long base = ((grow >> 8) * 128) * 256 + (grow & 255);
    int u0 = 8 * Wv + 2 * lq;
    hTt[base + (long)u0 * 256] = (unsigned short)(hp & 0xffff);
    hTt[base + (long)(u0 + 1) * 256] = (unsigned short)(hp >> 16);
  }
}

// ---------------- graph stage (r13 exact, verified) ------------------------
__global__ __launch_bounds__(256, 2) void g1_kernel(char* __restrict__ ws)
{
  const unsigned short* hTt = (const unsigned short*)(ws + O_HTT);
  const unsigned short* Apk = (const unsigned short*)(ws + O_APK);
  unsigned short* HAt = (unsigned short*)(ws + O_HAT);
  int tid = threadIdx.x, w = tid >> 6, l = tid & 63, lr = l & 15, lq = l >> 4;
  int bi = blockIdx.x;
  int b = bi >> 3, rtp = (bi >> 1) & 3, ch = bi & 1;
  f32x4 acc[2][2];
#pragma unroll
  for (int i = 0; i < 2; i++)
#pragma unroll
    for (int j = 0; j < 2; j++) acc[i][j] = (f32x4){0.f, 0.f, 0.f, 0.f};
  for (int kt = 0; kt < 8; kt++) {
    bf16x8 af[2];
#pragma unroll
    for (int rtl = 0; rtl < 2; rtl++) {
      int rt = rtp * 2 + rtl;
      af[rtl] = *(const bf16x8*)(hTt + (long)(b * 128 + 16 * rt + lr) * 256 + 32 * kt + 8 * lq);
    }
#pragma unroll
    for (int cti = 0; cti < 2; cti++) {
      int ct = w * 4 + ch * 2 + cti;
      bf16x8 bf = ((const bf16x8*)Apk)[(ct * 8 + kt) * 64 + l];
#pragma unroll
      for (int rtl = 0; rtl < 2; rtl++)
        acc[rtl][cti] = __builtin_amdgcn_mfma_f32_16x16x32_bf16(af[rtl], bf, acc[rtl][cti], 0, 0, 0);
    }
  }
#pragma unroll
  for (int rtl = 0; rtl < 2; rtl++)
#pragma unroll
    for (int cti = 0; cti < 2; cti++) {
      int rt = rtp * 2 + rtl, ct = w * 4 + ch * 2 + cti;
      u16x4 pk;
#pragma unroll
      for (int r = 0; r < 4; r++) pk[r] = f2bf(acc[rtl][cti][r]);
      *(u16x4*)(HAt + (long)(b * 256 + 16 * ct + lr) * 128 + 16 * rt + 4 * lq) = pk;
    }
}

__global__ __launch_bounds__(256, 2) void g2_kernel(char* __restrict__ ws)
{
  const unsigned short* HAt = (const unsigned short*)(ws + O_HAT);
  const unsigned short* W1apk = (const unsigned short*)(ws + O_W1APK);
  const unsigned short* W2apk = (const unsigned short*)(ws + O_W2APK);
  unsigned short* W1hAt = (unsigned short*)(ws + O_W1HAT);
  unsigned short* midT = (unsigned short*)(ws + O_MIDT);
  int tid = threadIdx.x, w = tid >> 6, l = tid & 63, lr = l & 15, lq = l >> 4;
  int bi = blockIdx.x;
  int b = bi >> 3, rtp = (bi >> 1) & 3, ch = bi & 1;
  f32x4 a1[2][2], a2[2][2];
#pragma unroll
  for (int i = 0; i < 2; i++)
#pragma unroll
    for (int j = 0; j < 2; j++) { a1[i][j] = (f32x4){0.f,0.f,0.f,0.f}; a2[i][j] = (f32x4){0.f,0.f,0.f,0.f}; }
  for (int kt = 0; kt < 4; kt++) {
    bf16x8 af1[2], af2[2];
#pragma unroll
    for (int rtl = 0; rtl < 2; rtl++) {
      int rt = rtp * 2 + rtl;
      af1[rtl] = ((const bf16x8*)W1apk)[(rt * 4 + kt) * 64 + l];
      af2[rtl] = ((const bf16x8*)W2apk)[(rt * 4 + kt) * 64 + l];
    }
#pragma unroll
    for (int cti = 0; cti < 2; cti++) {
      int ct = w * 4 + ch * 2 + cti;
      bf16x8 bf = *(const bf16x8*)(HAt + (long)(b * 256 + 16 * ct + lr) * 128 + 32 * kt + 8 * lq);
#pragma unroll
      for (int rtl = 0; rtl < 2; rtl++) {
        a1[rtl][cti] = __builtin_amdgcn_mfma_f32_16x16x32_bf16(af1[rtl], bf, a1[rtl][cti], 0, 0, 0);
        a2[rtl][cti] = __builtin_amdgcn_mfma_f32_16x16x32_bf16(af2[rtl], bf, a2[rtl][cti], 0, 0, 0);
      }
    }
  }
#pragma unroll
  for (int rtl = 0; rtl < 2; rtl++)
#pragma unroll
    for (int cti = 0; cti < 2; cti++) {
      int rt = rtp * 2 + rtl, ct = w * 4 + ch * 2 + cti;
      u16x4 p1, p2;
#pragma unroll
      for (int r = 0; r < 4; r++) {
        p1[r] = f2bf(a1[rtl][cti][r]);
        p2[r] = f2bf(fmaxf(a2[rtl][cti][r], 0.f));
      }
      long off = (long)(b * 256 + 16 * ct + lr) * 128 + 16 * rt + 4 * lq;
      *(u16x4*)(W1hAt + off) = p1;
      *(u16x4*)(midT + off) = p2;
    }
}

__global__ __launch_bounds__(256, 2) void g3_kernel(char* __restrict__ ws)
{
  const unsigned short* midT = (const unsigned short*)(ws + O_MIDT);
  const unsigned short* W3apk = (const unsigned short*)(ws + O_W3APK);
  unsigned short* W3r = (unsigned short*)(ws + O_W3R);
  int tid = threadIdx.x, w = tid >> 6, l = tid & 63, lr = l & 15, lq = l >> 4;
  int bi = blockIdx.x;
  int b = bi >> 3, rtp = (bi >> 1) & 3, ch = bi & 1;
  f32x4 acc[2][2];
#pragma unroll
  for (int i = 0; i < 2; i++)
#pragma unroll
    for (int j = 0; j < 2; j++) acc[i][j] = (f32x4){0.f, 0.f, 0.f, 0.f};
  for (int kt = 0; kt < 4; kt++) {
    bf16x8 af[2];
#pragma unroll
    for (int rtl = 0; rtl < 2; rtl++)
      af[rtl] = ((const bf16x8*)W3apk)[((rtp * 2 + rtl) * 4 + kt) * 64 + l];
#pragma unroll
    for (int cti = 0; cti < 2; cti++) {
      int ct = w * 4 + ch * 2 + cti;
      bf16x8 bf = *(const bf16x8*)(midT + (long)(b * 256 + 16 * ct + lr) * 128 + 32 * kt + 8 * lq);
#pragma unroll
      for (int rtl = 0; rtl < 2; rtl++)
        acc[rtl][cti] = __builtin_amdgcn_mfma_f32_16x16x32_bf16(af[rtl], bf, acc[rtl][cti], 0, 0, 0);
    }
  }
#pragma unroll
  for (int rtl = 0; rtl < 2; rtl++)
#pragma unroll
    for (int cti = 0; cti < 2; cti++) {
      int rt = rtp * 2 + rtl, ct = w * 4 + ch * 2 + cti;
#pragma unroll
      for (int r = 0; r < 4; r++)
        W3r[(long)(b * 128 + 16 * rt + 4 * lq + r) * 256 + 16 * ct + lr] = f2bf(acc[rtl][cti][r]);
    }
}

__global__ __launch_bounds__(256, 2) void g4_kernel(char* __restrict__ ws,
    const float* __restrict__ Wfc, float* __restrict__ out)
{
  const unsigned short* W3r = (const unsigned short*)(ws + O_W3R);
  const unsigned short* Apk = (const unsigned short*)(ws + O_APK);
  const unsigned short* W1hAt = (const unsigned short*)(ws + O_W1HAT);
  int tid = threadIdx.x, w = tid >> 6, l = tid & 63, lr = l & 15, lq = l >> 4;
  int bi = blockIdx.x;
  int b = bi >> 2, cq = bi & 3;
  int ct = cq * 4 + w;
  f32x4 acc[8];
#pragma unroll
  for (int i = 0; i < 8; i++) acc[i] = (f32x4){0.f, 0.f, 0.f, 0.f};
  for (int kt = 0; kt < 8; kt++) {
    bf16x8 bfv = ((const bf16x8*)Apk)[(ct * 8 + kt) * 64 + l];
#pragma unroll
    for (int rt = 0; rt < 8; rt++) {
      bf16x8 af = *(const bf16x8*)(W3r + (long)(b * 128 + 16 * rt + lr) * 256 + 32 * kt + 8 * lq);
      acc[rt] = __builtin_amdgcn_mfma_f32_16x16x32_bf16(af, bfv, acc[rt], 0, 0, 0);
    }
  }
  float psum = 0.f;
#pragma unroll
  for (int rt = 0; rt < 8; rt++) {
    float4 wf = *(const float4*)(Wfc + 16 * rt + 4 * lq);
    u16x4 wv = *(const u16x4*)(W1hAt + (long)(b * 256 + 16 * ct + lr) * 128 + 16 * rt + 4 * lq);
    psum += wf.x * (0.1f * acc[rt][0] + 0.9f * bf2f(wv[0]));
    psum += wf.y * (0.1f * acc[rt][1] + 0.9f * bf2f(wv[1]));
    psum += wf.z * (0.1f * acc[rt][2] + 0.9f * bf2f(wv[2]));
    psum += wf.w * (0.1f * acc[rt][3] + 0.9f * bf2f(wv[3]));
  }
  psum += __shfl_xor(psum, 16);
  psum += __shfl_xor(psum, 32);
  if (lq == 0) out[b * 256 + ct * 16 + lr] = __builtin_amdgcn_rcpf(1.f + fexp2(-1.44269504f * psum));
}

// ---------------------------------------------------------------------------
extern "C" void kernel_launch(void* const* d_in, const int* in_sizes, int n_in,
                              void* d_out, int out_size, void* d_ws, size_t ws_size,
                              hipStream_t stream)
{
  const float* x    = (const float*)d_in[0];
  const float* A    = (const float*)d_in[1];
  const float* Wih0 = (const float*)d_in[2];
  const float* Whh0 = (const float*)d_in[3];
  const float* bih0 = (const float*)d_in[4];
  const float* bhh0 = (const float*)d_in[5];
  const float* Wih1 = (const float*)d_in[6];
  const float* Whh1 = (const float*)d_in[7];
  const float* bih1 = (const float*)d_in[8];
  const float* bhh1 = (const float*)d_in[9];
  const float* W1   = (const float*)d_in[10];
  const float* W2   = (const float*)d_in[11];
  const float* W3   = (const float*)d_in[12];
  const float* Wfc  = (const float*)d_in[13];
  char* ws = (char*)d_ws;

  prep_all<<<(PREPALL_TOT + 255) / 256, 256, 0, stream>>>(
      x, A, Wih0, Whh0, bih0, bhh0, Wih1, Whh1, bih1, bhh1, W1, W2, W3, ws);

  size_t need_full = (size_t)O_H1 + 134217728u;  // 8192-row h1
  size_t need_half = (size_t)O_H1 + 67108864u;   // 4096-row h1
  if (ws_size >= need_full) {
    lstm0_k<<<256, 1024, 0, stream>>>(ws, 0);
    lstm1_k<<<256, 1024, 0, stream>>>(ws, 0);
  } else if (ws_size >= need_half) {
    for (int c = 0; c < 2; c++) {
      lstm0_k<<<128, 1024, 0, stream>>>(ws, c * 4096);
      lstm1_k<<<128, 1024, 0, stream>>>(ws, c * 4096);
    }
  } else {
    for (int c = 0; c < 4; c++) {
      lstm0_k<<<64, 1024, 0, stream>>>(ws, c * 2048);
      lstm1_k<<<64, 1024, 0, stream>>>(ws, c * 2048);
    }
  }

  g1_kernel<<<256, 256, 0, stream>>>(ws);
  g2_kernel<<<256, 256, 0, stream>>>(ws);
  g3_kernel<<<256, 256, 0, stream>>>(ws);
  g4_kernel<<<128, 256, 0, stream>>>(ws, Wfc, (float*)d_out);
}